// Round 7
// baseline (82.688 us; speedup 1.0000x reference)
//
#include <hip/hip_runtime.h>

#define NB1 64
#define B_RS 4

// workspace float offsets
#define W_K    0         // [64][1024] u64 packed (fkey<<32 | idx)
#define W_C    131072    // [64][1024] u32 counts
#define W_SB   196608    // [64][1024] f32 sum_b
#define W_SP   262144    // [64][1024] f32 p_sum
#define W_NS   327680    // [64][8] noise (cnt,sum per row)
#define A_QA   328192    // 1024 q_alpha
#define A_CF   329216    // 1024 qa/Nk
#define A_OR   330240    // 1024 int row of alpha
#define A_XLO  331264    // 1024 float4 alpha coords lo
#define A_XHI  335360    // 1024 float4 alpha coords hi
#define A_PSM  339456    // 1024 merged p_sum
#define A_KEYM 340480    // 1024 u32 seg-max key
#define A_SBM  341504    // 1024 merged sum_b
#define A_NKM  342528    // 1024 u32 merged count
#define A_CY0  343552    // 1024 float4 (-2x lo)
#define A_CY1  347648    // 1024 float4 (-2x hi)
#define A_CCC  351744    // 1024 float2 (ck2+1e-6, cf)
#define A_OC   353792    // 4 obj_cnt per row
#define A_AR   353796    // 4 reps x 8 (att[4], rep[4]) row accumulators
#define A_LSE  353828    // 8 reps x 1024 LSE sums

__device__ __forceinline__ unsigned fkey(float f) {
    unsigned u = __float_as_uint(f);
    return ((int)u < 0) ? ~u : (u | 0x80000000u);
}
__device__ __forceinline__ float fdec(unsigned k) {
    unsigned u = ((int)k < 0) ? (k & 0x7fffffffu) : ~k;
    return __uint_as_float(u);
}

// ---- P1: block-local LDS aggregation, private-slice flush (no global atomics, no init kernel) ----
__global__ __launch_bounds__(512) void k_p1(const float* __restrict__ beta,
                                            const int* __restrict__ asso,
                                            const int* __restrict__ rs,
                                            float* __restrict__ w, int N) {
    __shared__ unsigned long long sk[1024];
    __shared__ unsigned sc[1024];
    __shared__ float ssb[1024], ssp[1024];
    __shared__ float ns[8];
    int t = threadIdx.x, b = blockIdx.x;
    for (int j = t; j < 1024; j += 512) { sk[j] = 0ull; sc[j] = 0u; ssb[j] = 0.f; ssp[j] = 0.f; }
    if (t < 8) ns[t] = 0.f;
    int rs1 = rs[1], rs2 = rs[2], rs3 = rs[3];
    __syncthreads();
    for (int i = b * 512 + t; i < N; i += NB1 * 512) {
        float bv = beta[i];
        int a = asso[i];
        float bc = fminf(fmaxf(bv, 0.f), 0.999f);
        float ath = 0.5f * __logf(__fdividef(1.f + bc, 1.f - bc));
        float at2 = ath * ath;
        float pv = fmaxf(at2, 1e-6f);
        if (a >= 0) {
            unsigned long long pk = (((unsigned long long)fkey(bv)) << 32) | (unsigned)i;
            atomicMax(&sk[a], pk);
            atomicAdd(&sc[a], 1u);
            atomicAdd(&ssb[a], bv);
            atomicAdd(&ssp[a], pv);
        } else {
            int r = (i >= rs1) + (i >= rs2) + (i >= rs3);
            atomicAdd(&ns[2 * r], 1.f);
            atomicAdd(&ns[2 * r + 1], bv);
        }
    }
    __syncthreads();
    for (int j = t; j < 1024; j += 512) {
        ((unsigned long long*)w)[(b << 10) + j] = sk[j];
        ((unsigned*)w)[W_C + (b << 10) + j] = sc[j];
        w[W_SB + (b << 10) + j] = ssb[j];
        w[W_SP + (b << 10) + j] = ssp[j];
    }
    if (t < 8) w[W_NS + b * 8 + t] = ns[t];
}

// ---- M1: merge slices, finalize cluster tables, obj_cnt, zero LSE/AR ----
__global__ __launch_bounds__(256) void k_m1(const float* __restrict__ beta,
                                            const float* __restrict__ coords,
                                            const int* __restrict__ rs,
                                            float* __restrict__ w) {
    __shared__ int oc0;
    int t = threadIdx.x, r = blockIdx.x;
    if (t == 0) oc0 = 0;
    int k = (r << 8) + t;
    unsigned long long k64 = 0ull;
    unsigned cnt = 0u;
    float sb = 0.f, sp = 0.f;
#pragma unroll 4
    for (int rp = 0; rp < NB1; ++rp) {
        unsigned long long v = ((const unsigned long long*)w)[(rp << 10) + k];
        k64 = v > k64 ? v : k64;
        cnt += ((const unsigned*)w)[W_C + (rp << 10) + k];
        sb += w[W_SB + (rp << 10) + k];
        sp += w[W_SP + (rp << 10) + k];
    }
    bool ov = cnt > 0u;
    int ai = (int)(unsigned)(k64 & 0xffffffffull);
    float4 x0 = ((const float4*)coords)[ai * 2];
    float4 x1 = ((const float4*)coords)[ai * 2 + 1];
    float ba = beta[ai];
    float bca = fminf(fmaxf(ba, 0.f), 0.999f);
    float ata = atanhf(bca);
    float qa = ov ? ata * ata + 0.1f : 0.f;
    int rs1 = rs[1], rs2 = rs[2], rs3 = rs[3];
    int orr = (ai >= rs1) + (ai >= rs2) + (ai >= rs3);
    float cf = qa / fmaxf((float)cnt, 1.f);
    w[A_QA + k] = qa;
    w[A_CF + k] = cf;
    ((int*)w)[A_OR + k] = orr;
    ((float4*)(w + A_XLO))[k] = x0;
    ((float4*)(w + A_XHI))[k] = x1;
    w[A_PSM + k] = sp;
    ((unsigned*)w)[A_KEYM + k] = (unsigned)(k64 >> 32);
    w[A_SBM + k] = sb;
    ((unsigned*)w)[A_NKM + k] = cnt;
    ((float4*)(w + A_CY0))[k] = make_float4(-2.f * x0.x, -2.f * x0.y, -2.f * x0.z, -2.f * x0.w);
    ((float4*)(w + A_CY1))[k] = make_float4(-2.f * x1.x, -2.f * x1.y, -2.f * x1.z, -2.f * x1.w);
    float ck2 = x0.x * x0.x + x0.y * x0.y + x0.z * x0.z + x0.w * x0.w +
                x1.x * x1.x + x1.y * x1.y + x1.z * x1.z + x1.w * x1.w;
    ((float2*)(w + A_CCC))[k] = make_float2(ck2 + 1e-6f, cf);
    // zero LSE slice + AR accumulators (next dispatch's atomics)
    for (int j = t; j < 2048; j += 256) w[A_LSE + (r << 11) + j] = 0.f;
    if (r == 0 && t < 32) w[A_AR + t] = 0.f;
    __syncthreads();
    unsigned long long bal = __ballot(ov);
    if ((t & 63) == 0) atomicAdd(&oc0, __popcll(bal));
    __syncthreads();
    if (t == 0) w[A_OC + r] = (float)oc0;
}

// ---- P4: N x K_row via wave-uniform scalar loads + fused epilogue (incl. LSE) ----
__global__ __launch_bounds__(512) void k_p4(const float* __restrict__ beta,
                                            const float* __restrict__ coords,
                                            const int* __restrict__ asso,
                                            const int* __restrict__ rs,
                                            const float* __restrict__ wc,
                                            float* __restrict__ lse,
                                            float* __restrict__ ar,
                                            float* __restrict__ out, int N) {
    __shared__ float bins[8];
    int t = threadIdx.x, bid = blockIdx.x;
    if (t < 8) bins[t] = 0.f;
    __syncthreads();
    int rs1 = rs[1], rs2 = rs[2], rs3 = rs[3];
    int base = bid * 512;
    int r0 = (base >= rs1) + (base >= rs2) + (base >= rs3);
    int lastp = min(base + 511, N - 1);
    int rl = (lastp >= rs1) + (lastp >= rs2) + (lastp >= rs3);
    int i = base + t;
    float att = 0.f, rep = 0.f;
    int r = r0;
    if (i < N) {
        const float4* cp = (const float4*)(coords + (size_t)i * 8);
        float4 c0 = cp[0], c1 = cp[1];
        float cn2 = c0.x * c0.x + c0.y * c0.y + c0.z * c0.z + c0.w * c0.w +
                    c1.x * c1.x + c1.y * c1.y + c1.z * c1.z + c1.w * c1.w;
        r = (i >= rs1) + (i >= rs2) + (i >= rs3);
        float bv = beta[i];
        int aa = asso[i];
        float bc = fminf(fmaxf(bv, 0.f), 0.999f);
        float ath = 0.5f * __logf(__fdividef(1.f + bc, 1.f - bc));
        float at2 = ath * ath;
        float q = at2 + 0.1f;
        float pv = fmaxf(at2, 1e-6f);
        const float4* cy0 = (const float4*)(wc + A_CY0);
        const float4* cy1 = (const float4*)(wc + A_CY1);
        const float2* ccc = (const float2*)(wc + A_CCC);
        float acc = 0.f;
        for (int rr = r0; rr <= rl; ++rr) {   // uniform row loop (1, rarely 2)
            int k0 = rr << 8;
            float accL = 0.f;
#pragma unroll 4
            for (int j = 0; j < 256; ++j) {
                float4 y0 = cy0[k0 + j];
                float4 y1 = cy1[k0 + j];
                float2 cc = ccc[k0 + j];
                float d = cn2 + cc.x;
                d = fmaf(y0.x, c0.x, d); d = fmaf(y0.y, c0.y, d);
                d = fmaf(y0.z, c0.z, d); d = fmaf(y0.w, c0.w, d);
                d = fmaf(y1.x, c1.x, d); d = fmaf(y1.y, c1.y, d);
                d = fmaf(y1.z, c1.z, d); d = fmaf(y1.w, c1.w, d);
                d = fmaxf(d, 1e-6f);
                float v = fmaxf(1.f - sqrtf(d), 0.f);
                accL = fmaf(v, cc.y, accL);
            }
            if (r == rr) acc = accL;
        }
        bool valid = aa >= 0;
        int kk = valid ? aa : 0;
        if (valid) {
            float4 xk0 = ((const float4*)(wc + A_XLO))[kk];
            float4 xk1 = ((const float4*)(wc + A_XHI))[kk];
            float qak = wc[A_QA + kk];
            float d0 = c0.x - xk0.x, d1 = c0.y - xk0.y, d2 = c0.z - xk0.z, d3 = c0.w - xk0.w;
            float d4 = c1.x - xk1.x, d5 = c1.y - xk1.y, d6 = c1.z - xk1.z, d7 = c1.w - xk1.w;
            float dsq = d0 * d0 + d1 * d1 + d2 * d2 + d3 * d3 +
                        d4 * d4 + d5 * d5 + d6 * d6 + d7 * d7;
            att = q * qak * dsq;
            int ork = ((const int*)wc)[A_OR + kk];
            if (ork == r) {
                float ck2 = xk0.x * xk0.x + xk0.y * xk0.y + xk0.z * xk0.z + xk0.w * xk0.w +
                            xk1.x * xk1.x + xk1.y * xk1.y + xk1.z * xk1.z + xk1.w * xk1.w;
                float dotk = c0.x * xk0.x + c0.y * xk0.y + c0.z * xk0.z + c0.w * xk0.w +
                             c1.x * xk1.x + c1.y * xk1.y + c1.z * xk1.z + c1.w * xk1.w;
                float d = fmaxf(cn2 + ck2 - 2.f * dotk, 0.f) + 1e-6f;
                float vk = fmaxf(1.f - sqrtf(d), 0.f);
                acc -= vk * wc[A_CF + kk];
            }
            float m = fdec(((const unsigned*)wc)[A_KEYM + kk]);
            atomicAdd(&lse[((bid & 7) << 10) + kk], __expf((bv - m) * 1000.f));
        }
        rep = q * acc;
        float psum = wc[A_PSM + kk];
        float ocnt = wc[A_OC + r];
        float pl = valid ? pv / fmaxf(psum, 1e-6f) / fmaxf(ocnt, 1.f) * 0.25f : 0.f;
        out[3 + i] = pl;
        out[3 + N + i] = att + rep;
    }
    int lane = t & 63;
    int rA = __shfl(r, 0);
    bool uni = __all(r == rA);
    if (uni) {
        float aS = att, rS = rep;
#pragma unroll
        for (int o = 32; o; o >>= 1) { aS += __shfl_xor(aS, o); rS += __shfl_xor(rS, o); }
        if (lane == 0) { atomicAdd(&bins[rA], aS); atomicAdd(&bins[4 + rA], rS); }
    } else if (i < N) {
        atomicAdd(&bins[r], att);
        atomicAdd(&bins[4 + r], rep);
    }
    __syncthreads();
    if (t < 8) atomicAdd(&ar[(bid & 3) * 8 + t], bins[t]);
}

// ---- P5: bpen + all final reductions ----
__global__ __launch_bounds__(1024) void k_p5(const int* __restrict__ rs,
                                             const float* __restrict__ w,
                                             float* __restrict__ out) {
    __shared__ float op[4];
    __shared__ float nsb[8];
    __shared__ float arr[8];
    int t = threadIdx.x;
    if (t < 4) op[t] = 0.f;
    __syncthreads();
    int k = t;
    float ls = 0.f;
#pragma unroll
    for (int rp = 0; rp < 8; ++rp) ls += w[A_LSE + (rp << 10) + k];
    unsigned cnt = ((const unsigned*)w)[A_NKM + k];
    bool ov = cnt > 0u;
    float m = ov ? fdec(((const unsigned*)w)[A_KEYM + k]) : 0.f;
    float lsev = m + 0.001f * logf(ls + 1e-30f);
    float sbc = fminf(fmaxf(w[A_SBM + k], 0.f), 1.f);
    float bpen = ov ? (1.f - lsev) + (1.f - sbc) : 0.f;
    float v = bpen;
#pragma unroll
    for (int o = 32; o; o >>= 1) v += __shfl_xor(v, o);
    if ((t & 63) == 0) atomicAdd(&op[k >> 8], v);
    if (t < 8) {
        float a = 0.f;
        for (int b = 0; b < NB1; ++b) a += w[W_NS + b * 8 + t];
        nsb[t] = a;
    } else if (t < 16) {
        int s = t - 8;
        float a = 0.f;
#pragma unroll
        for (int rep = 0; rep < 4; ++rep) a += w[A_AR + rep * 8 + s];
        arr[s] = a;
    }
    __syncthreads();
    if (t == 0) {
        float lv = 0.f, lr = 0.f, lb = 0.f;
        for (int r = 0; r < B_RS; ++r) {
            float len = (float)(rs[r + 1] - rs[r]);
            lv += arr[r] / len;
            lr += arr[4 + r] / len;
            float oc = w[A_OC + r];
            lb += op[r] / fmaxf(oc, 1.f) + nsb[2 * r + 1] / fmaxf(nsb[2 * r], 1.f);
        }
        out[0] = lv * 0.25f;
        out[1] = lr * 0.25f;
        out[2] = lb * 0.25f;
    }
}

extern "C" void kernel_launch(void* const* d_in, const int* in_sizes, int n_in,
                              void* d_out, int out_size, void* d_ws, size_t ws_size,
                              hipStream_t stream) {
    const float* beta = (const float*)d_in[0];
    const float* coords = (const float*)d_in[1];
    const int* asso = (const int*)d_in[2];
    const int* rs = (const int*)d_in[3];
    int N = in_sizes[0];
    float* w = (float*)d_ws;
    float* out = (float*)d_out;
    int nb4 = (N + 511) / 512;
    hipLaunchKernelGGL(k_p1, dim3(NB1), dim3(512), 0, stream, beta, asso, rs, w, N);
    hipLaunchKernelGGL(k_m1, dim3(4), dim3(256), 0, stream, beta, coords, rs, w);
    hipLaunchKernelGGL(k_p4, dim3(nb4), dim3(512), 0, stream, beta, coords, asso, rs,
                       w, w + A_LSE, w + A_AR, out, N);
    hipLaunchKernelGGL(k_p5, dim3(1), dim3(1024), 0, stream, rs, w, out);
}

// Round 8
// 72.358 us; speedup vs baseline: 1.1428x; 1.1428x over previous
//
#include <hip/hip_runtime.h>

#define NB1 64
#define B_RS 4

// workspace float offsets
#define W_K    0         // [64][1024] u64 packed (fkey<<32 | idx)
#define W_C    131072    // [64][1024] u32 counts
#define W_SB   196608    // [64][1024] f32 sum_b
#define W_SP   262144    // [64][1024] f32 p_sum
#define W_NS   327680    // [64][8] noise (cnt,sum per row)
#define A_QA   328192    // 1024 q_alpha
#define A_CF   329216    // 1024 qa/Nk
#define A_OR   330240    // 1024 int row of alpha
#define A_XLO  331264    // 1024 float4 alpha coords lo
#define A_XHI  335360    // 1024 float4 alpha coords hi
#define A_PSM  339456    // 1024 merged p_sum
#define A_KEYM 340480    // 1024 u32 seg-max key
#define A_SBM  341504    // 1024 merged sum_b
#define A_NKM  342528    // 1024 u32 merged count
#define A_CY0  343552    // 1024 float4 (-2x lo)
#define A_CY1  347648    // 1024 float4 (-2x hi)
#define A_CCC  351744    // 1024 float2 (ck2+1e-6, cf)
#define A_OC   353792    // 4 obj_cnt per row
#define A_LSE  353800    // 8 x 1024 LSE slices
#define A_QS   361992    // q[N] | p[N] | rep slices 4*N | p6 partials

__device__ __forceinline__ unsigned fkey(float f) {
    unsigned u = __float_as_uint(f);
    return ((int)u < 0) ? ~u : (u | 0x80000000u);
}
__device__ __forceinline__ float fdec(unsigned k) {
    unsigned u = ((int)k < 0) ? (k & 0x7fffffffu) : ~k;
    return __uint_as_float(u);
}

// ---- P1: block-local LDS aggregation, private-slice flush ----
__global__ __launch_bounds__(512) void k_p1(const float* __restrict__ beta,
                                            const int* __restrict__ asso,
                                            const int* __restrict__ rs,
                                            float* __restrict__ w, int N) {
    __shared__ unsigned long long sk[1024];
    __shared__ unsigned sc[1024];
    __shared__ float ssb[1024], ssp[1024];
    __shared__ float ns[8];
    int t = threadIdx.x, b = blockIdx.x;
    for (int j = t; j < 1024; j += 512) { sk[j] = 0ull; sc[j] = 0u; ssb[j] = 0.f; ssp[j] = 0.f; }
    if (t < 8) ns[t] = 0.f;
    int rs1 = rs[1], rs2 = rs[2], rs3 = rs[3];
    __syncthreads();
    for (int i = b * 512 + t; i < N; i += NB1 * 512) {
        float bv = beta[i];
        int a = asso[i];
        float bc = fminf(fmaxf(bv, 0.f), 0.999f);
        float ath = 0.5f * __logf(__fdividef(1.f + bc, 1.f - bc));
        float at2 = ath * ath;
        float pv = fmaxf(at2, 1e-6f);
        w[A_QS + i] = at2 + 0.1f;
        w[A_QS + N + i] = pv;
        if (a >= 0) {
            unsigned long long pk = (((unsigned long long)fkey(bv)) << 32) | (unsigned)i;
            atomicMax(&sk[a], pk);
            atomicAdd(&sc[a], 1u);
            atomicAdd(&ssb[a], bv);
            atomicAdd(&ssp[a], pv);
        } else {
            int r = (i >= rs1) + (i >= rs2) + (i >= rs3);
            atomicAdd(&ns[2 * r], 1.f);
            atomicAdd(&ns[2 * r + 1], bv);
        }
    }
    __syncthreads();
    for (int j = t; j < 1024; j += 512) {
        ((unsigned long long*)w)[(b << 10) + j] = sk[j];
        ((unsigned*)w)[W_C + (b << 10) + j] = sc[j];
        w[W_SB + (b << 10) + j] = ssb[j];
        w[W_SP + (b << 10) + j] = ssp[j];
    }
    if (t < 8) w[W_NS + b * 8 + t] = ns[t];
}

// ---- M1: merge slices, finalize cluster tables, obj_cnt, zero LSE ----
__global__ __launch_bounds__(256) void k_m1(const float* __restrict__ beta,
                                            const float* __restrict__ coords,
                                            const int* __restrict__ rs,
                                            float* __restrict__ w) {
    __shared__ int oc0;
    int t = threadIdx.x, r = blockIdx.x;
    if (t == 0) oc0 = 0;
    int k = (r << 8) + t;
    unsigned long long k64 = 0ull;
    unsigned cnt = 0u;
    float sb = 0.f, sp = 0.f;
#pragma unroll 4
    for (int rp = 0; rp < NB1; ++rp) {
        unsigned long long v = ((const unsigned long long*)w)[(rp << 10) + k];
        k64 = v > k64 ? v : k64;
        cnt += ((const unsigned*)w)[W_C + (rp << 10) + k];
        sb += w[W_SB + (rp << 10) + k];
        sp += w[W_SP + (rp << 10) + k];
    }
    bool ov = cnt > 0u;
    int ai = (int)(unsigned)(k64 & 0xffffffffull);
    float4 x0 = ((const float4*)coords)[ai * 2];
    float4 x1 = ((const float4*)coords)[ai * 2 + 1];
    float ba = beta[ai];
    float bca = fminf(fmaxf(ba, 0.f), 0.999f);
    float ata = atanhf(bca);
    float qa = ov ? ata * ata + 0.1f : 0.f;
    int rs1 = rs[1], rs2 = rs[2], rs3 = rs[3];
    int orr = (ai >= rs1) + (ai >= rs2) + (ai >= rs3);
    float cf = qa / fmaxf((float)cnt, 1.f);
    w[A_QA + k] = qa;
    w[A_CF + k] = cf;
    ((int*)w)[A_OR + k] = orr;
    ((float4*)(w + A_XLO))[k] = x0;
    ((float4*)(w + A_XHI))[k] = x1;
    w[A_PSM + k] = sp;
    ((unsigned*)w)[A_KEYM + k] = (unsigned)(k64 >> 32);
    w[A_SBM + k] = sb;
    ((unsigned*)w)[A_NKM + k] = cnt;
    ((float4*)(w + A_CY0))[k] = make_float4(-2.f * x0.x, -2.f * x0.y, -2.f * x0.z, -2.f * x0.w);
    ((float4*)(w + A_CY1))[k] = make_float4(-2.f * x1.x, -2.f * x1.y, -2.f * x1.z, -2.f * x1.w);
    float ck2 = x0.x * x0.x + x0.y * x0.y + x0.z * x0.z + x0.w * x0.w +
                x1.x * x1.x + x1.y * x1.y + x1.z * x1.z + x1.w * x1.w;
    ((float2*)(w + A_CCC))[k] = make_float2(ck2 + 1e-6f, cf);
    for (int j = t; j < 2048; j += 256) w[A_LSE + (r << 11) + j] = 0.f;
    __syncthreads();
    unsigned long long bal = __ballot(ov);
    if ((t & 63) == 0) atomicAdd(&oc0, __popcll(bal));
    __syncthreads();
    if (t == 0) w[A_OC + r] = (float)oc0;
}

// ---- P4: pure repulsion partials, chunked, LDS-broadcast, 2pt/thread ----
__global__ __launch_bounds__(256) void k_p4(const float* __restrict__ coords,
                                            const int* __restrict__ rs,
                                            const float* __restrict__ wc,
                                            float* __restrict__ repout, int N) {
    __shared__ float4 sY0[128];
    __shared__ float4 sY1[128];
    __shared__ float2 sCC[128];
    int t = threadIdx.x, bid = blockIdx.x;
    int pc = bid >> 2, cc = bid & 3;
    int base = pc << 9;
    int rs1 = rs[1], rs2 = rs[2], rs3 = rs[3];
    int r0 = (base >= rs1) + (base >= rs2) + (base >= rs3);
    int lastp = min(base + 511, N - 1);
    int rl = (lastp >= rs1) + (lastp >= rs2) + (lastp >= rs3);
    const float4* cy0 = (const float4*)(wc + A_CY0);
    const float4* cy1 = (const float4*)(wc + A_CY1);
    const float2* ccc = (const float2*)(wc + A_CCC);
    if (t < 64) {
        int k0 = (r0 << 8) + (cc << 6) + t;
        sY0[t] = cy0[k0]; sY1[t] = cy1[k0]; sCC[t] = ccc[k0];
    }
    if (rl != r0 && t >= 64 && t < 128) {
        int j = t - 64;
        int k1 = (rl << 8) + (cc << 6) + j;
        sY0[64 + j] = cy0[k1]; sY1[64 + j] = cy1[k1]; sCC[64 + j] = ccc[k1];
    }
    __syncthreads();
    int i0 = base + 2 * t, i1 = i0 + 1;
    bool in0 = i0 < N, in1 = i1 < N;
    if (!in0) return;
    const float4* cp = (const float4*)(coords + (size_t)i0 * 8);
    float4 c00 = cp[0], c01 = cp[1], c10, c11;
    float cn20 = c00.x * c00.x + c00.y * c00.y + c00.z * c00.z + c00.w * c00.w +
                 c01.x * c01.x + c01.y * c01.y + c01.z * c01.z + c01.w * c01.w;
    float cn21 = 0.f;
    int rr0 = (i0 >= rs1) + (i0 >= rs2) + (i0 >= rs3);
    int rr1 = rr0;
    if (in1) {
        c10 = cp[2]; c11 = cp[3];
        cn21 = c10.x * c10.x + c10.y * c10.y + c10.z * c10.z + c10.w * c10.w +
               c11.x * c11.x + c11.y * c11.y + c11.z * c11.z + c11.w * c11.w;
        rr1 = (i1 >= rs1) + (i1 >= rs2) + (i1 >= rs3);
    }
    int s0 = (rr0 == r0) ? 0 : 64;
    int s1 = (rr1 == r0) ? 0 : 64;
    float acc0 = 0.f, acc1 = 0.f;
    if (in1 && s0 == s1) {
#pragma unroll 2
        for (int j = s0; j < s0 + 64; ++j) {
            float4 y0 = sY0[j];
            float4 y1 = sY1[j];
            float2 cx = sCC[j];
            float d0 = cn20 + cx.x, d1 = cn21 + cx.x;
            d0 = fmaf(y0.x, c00.x, d0); d1 = fmaf(y0.x, c10.x, d1);
            d0 = fmaf(y0.y, c00.y, d0); d1 = fmaf(y0.y, c10.y, d1);
            d0 = fmaf(y0.z, c00.z, d0); d1 = fmaf(y0.z, c10.z, d1);
            d0 = fmaf(y0.w, c00.w, d0); d1 = fmaf(y0.w, c10.w, d1);
            d0 = fmaf(y1.x, c01.x, d0); d1 = fmaf(y1.x, c11.x, d1);
            d0 = fmaf(y1.y, c01.y, d0); d1 = fmaf(y1.y, c11.y, d1);
            d0 = fmaf(y1.z, c01.z, d0); d1 = fmaf(y1.z, c11.z, d1);
            d0 = fmaf(y1.w, c01.w, d0); d1 = fmaf(y1.w, c11.w, d1);
            d0 = fmaxf(d0, 1e-6f); d1 = fmaxf(d1, 1e-6f);
            float v0 = fmaxf(1.f - sqrtf(d0), 0.f);
            float v1 = fmaxf(1.f - sqrtf(d1), 0.f);
            acc0 = fmaf(v0, cx.y, acc0);
            acc1 = fmaf(v1, cx.y, acc1);
        }
    } else {
#pragma unroll 2
        for (int j = s0; j < s0 + 64; ++j) {
            float4 y0 = sY0[j]; float4 y1 = sY1[j]; float2 cx = sCC[j];
            float d = cn20 + cx.x;
            d = fmaf(y0.x, c00.x, d); d = fmaf(y0.y, c00.y, d);
            d = fmaf(y0.z, c00.z, d); d = fmaf(y0.w, c00.w, d);
            d = fmaf(y1.x, c01.x, d); d = fmaf(y1.y, c01.y, d);
            d = fmaf(y1.z, c01.z, d); d = fmaf(y1.w, c01.w, d);
            d = fmaxf(d, 1e-6f);
            acc0 = fmaf(fmaxf(1.f - sqrtf(d), 0.f), cx.y, acc0);
        }
        if (in1) {
#pragma unroll 2
            for (int j = s1; j < s1 + 64; ++j) {
                float4 y0 = sY0[j]; float4 y1 = sY1[j]; float2 cx = sCC[j];
                float d = cn21 + cx.x;
                d = fmaf(y0.x, c10.x, d); d = fmaf(y0.y, c10.y, d);
                d = fmaf(y0.z, c10.z, d); d = fmaf(y0.w, c10.w, d);
                d = fmaf(y1.x, c11.x, d); d = fmaf(y1.y, c11.y, d);
                d = fmaf(y1.z, c11.z, d); d = fmaf(y1.w, c11.w, d);
                d = fmaxf(d, 1e-6f);
                acc1 = fmaf(fmaxf(1.f - sqrtf(d), 0.f), cx.y, acc1);
            }
        }
    }
    float* ro = repout + (size_t)cc * N;
    if (in1) *(float2*)(ro + i0) = make_float2(acc0, acc1);
    else ro[i0] = acc0;
}

// ---- P6: combine partials, attraction, own-term, pl, LSE, outputs, row bins ----
__global__ __launch_bounds__(256) void k_p6(const float* __restrict__ beta,
                                            const float* __restrict__ coords,
                                            const int* __restrict__ asso,
                                            const int* __restrict__ rs,
                                            const float* __restrict__ wc,
                                            const float* __restrict__ repin,
                                            float* __restrict__ lse,
                                            float* __restrict__ p6p,
                                            float* __restrict__ out, int N) {
    __shared__ float bins[8];
    int t = threadIdx.x, bid = blockIdx.x;
    if (t < 8) bins[t] = 0.f;
    int rs1 = rs[1], rs2 = rs[2], rs3 = rs[3];
    __syncthreads();
    int i = bid * 256 + t;
    float att = 0.f, rep = 0.f;
    int r = 0;
    if (i < N) {
        float racc = repin[i] + repin[(size_t)N + i] + repin[2 * (size_t)N + i] + repin[3 * (size_t)N + i];
        r = (i >= rs1) + (i >= rs2) + (i >= rs3);
        const float4* cp = (const float4*)(coords + (size_t)i * 8);
        float4 c0 = cp[0], c1 = cp[1];
        float q = wc[A_QS + i];
        float pv = wc[A_QS + N + i];
        int aa = asso[i];
        bool valid = aa >= 0;
        int kk = valid ? aa : 0;
        if (valid) {
            float4 xk0 = ((const float4*)(wc + A_XLO))[kk];
            float4 xk1 = ((const float4*)(wc + A_XHI))[kk];
            float qak = wc[A_QA + kk];
            float d0 = c0.x - xk0.x, d1 = c0.y - xk0.y, d2 = c0.z - xk0.z, d3 = c0.w - xk0.w;
            float d4 = c1.x - xk1.x, d5 = c1.y - xk1.y, d6 = c1.z - xk1.z, d7 = c1.w - xk1.w;
            float dsq = d0 * d0 + d1 * d1 + d2 * d2 + d3 * d3 +
                        d4 * d4 + d5 * d5 + d6 * d6 + d7 * d7;
            att = q * qak * dsq;
            int ork = ((const int*)wc)[A_OR + kk];
            if (ork == r) {
                float cn2 = c0.x * c0.x + c0.y * c0.y + c0.z * c0.z + c0.w * c0.w +
                            c1.x * c1.x + c1.y * c1.y + c1.z * c1.z + c1.w * c1.w;
                float ck2 = xk0.x * xk0.x + xk0.y * xk0.y + xk0.z * xk0.z + xk0.w * xk0.w +
                            xk1.x * xk1.x + xk1.y * xk1.y + xk1.z * xk1.z + xk1.w * xk1.w;
                float dotk = c0.x * xk0.x + c0.y * xk0.y + c0.z * xk0.z + c0.w * xk0.w +
                             c1.x * xk1.x + c1.y * xk1.y + c1.z * xk1.z + c1.w * xk1.w;
                float d = fmaxf(cn2 + ck2 - 2.f * dotk, 0.f) + 1e-6f;
                float vk = fmaxf(1.f - sqrtf(d), 0.f);
                racc -= vk * wc[A_CF + kk];
            }
            float bv = beta[i];
            float m = fdec(((const unsigned*)wc)[A_KEYM + kk]);
            atomicAdd(&lse[((bid & 7) << 10) + kk], __expf((bv - m) * 1000.f));
        }
        rep = q * racc;
        float psum = wc[A_PSM + kk];
        float ocnt = wc[A_OC + r];
        float pl = valid ? pv / fmaxf(psum, 1e-6f) / fmaxf(ocnt, 1.f) * 0.25f : 0.f;
        out[3 + i] = pl;
        out[3 + N + i] = att + rep;
    }
    int lane = t & 63;
    int rA = __shfl(r, 0);
    bool uni = __all(r == rA);
    if (uni) {
        float aS = att, rS = rep;
#pragma unroll
        for (int o = 32; o; o >>= 1) { aS += __shfl_xor(aS, o); rS += __shfl_xor(rS, o); }
        if (lane == 0) { atomicAdd(&bins[rA], aS); atomicAdd(&bins[4 + rA], rS); }
    } else if (i < N) {
        atomicAdd(&bins[r], att);
        atomicAdd(&bins[4 + r], rep);
    }
    __syncthreads();
    if (t < 8) p6p[bid * 8 + t] = bins[t];
}

// ---- P5: bpen + all final reductions ----
__global__ __launch_bounds__(1024) void k_p5(const int* __restrict__ rs,
                                             const float* __restrict__ w,
                                             const float* __restrict__ p6p, int nb,
                                             float* __restrict__ out) {
    __shared__ float op[4];
    __shared__ float nsb[8];
    __shared__ float ar8[8][9];
    int t = threadIdx.x;
    if (t < 4) op[t] = 0.f;
    __syncthreads();
    int k = t;
    float ls = 0.f;
#pragma unroll
    for (int rp = 0; rp < 8; ++rp) ls += w[A_LSE + (rp << 10) + k];
    unsigned cnt = ((const unsigned*)w)[A_NKM + k];
    bool ov = cnt > 0u;
    float m = ov ? fdec(((const unsigned*)w)[A_KEYM + k]) : 0.f;
    float lsev = m + 0.001f * logf(ls + 1e-30f);
    float sbc = fminf(fmaxf(w[A_SBM + k], 0.f), 1.f);
    float bpen = ov ? (1.f - lsev) + (1.f - sbc) : 0.f;
    float v = bpen;
#pragma unroll
    for (int o = 32; o; o >>= 1) v += __shfl_xor(v, o);
    if ((t & 63) == 0) atomicAdd(&op[k >> 8], v);
    if (t < 64) {
        int slot = t & 7, part = t >> 3;
        float acc = 0.f;
        for (int j = part; j < nb; j += 8) acc += p6p[j * 8 + slot];
        ar8[slot][part] = acc;
    } else if (t < 72) {
        int s = t - 64;
        float a = 0.f;
        for (int b = 0; b < NB1; ++b) a += w[W_NS + b * 8 + s];
        nsb[s] = a;
    }
    __syncthreads();
    if (t == 0) {
        float lv = 0.f, lr = 0.f, lb = 0.f;
        for (int r = 0; r < B_RS; ++r) {
            float a = 0.f, rp = 0.f;
            for (int j = 0; j < 8; ++j) { a += ar8[r][j]; rp += ar8[4 + r][j]; }
            float len = (float)(rs[r + 1] - rs[r]);
            lv += a / len;
            lr += rp / len;
            float oc = w[A_OC + r];
            lb += op[r] / fmaxf(oc, 1.f) + nsb[2 * r + 1] / fmaxf(nsb[2 * r], 1.f);
        }
        out[0] = lv * 0.25f;
        out[1] = lr * 0.25f;
        out[2] = lb * 0.25f;
    }
}

extern "C" void kernel_launch(void* const* d_in, const int* in_sizes, int n_in,
                              void* d_out, int out_size, void* d_ws, size_t ws_size,
                              hipStream_t stream) {
    const float* beta = (const float*)d_in[0];
    const float* coords = (const float*)d_in[1];
    const int* asso = (const int*)d_in[2];
    const int* rs = (const int*)d_in[3];
    int N = in_sizes[0];
    float* w = (float*)d_ws;
    float* out = (float*)d_out;
    int nbp = (N + 511) / 512;
    int nb6 = (N + 255) / 256;
    float* repb = w + A_QS + 2 * (size_t)N;
    float* p6p = repb + 4 * (size_t)N;
    hipLaunchKernelGGL(k_p1, dim3(NB1), dim3(512), 0, stream, beta, asso, rs, w, N);
    hipLaunchKernelGGL(k_m1, dim3(4), dim3(256), 0, stream, beta, coords, rs, w);
    hipLaunchKernelGGL(k_p4, dim3(nbp * 4), dim3(256), 0, stream, coords, rs, w, repb, N);
    hipLaunchKernelGGL(k_p6, dim3(nb6), dim3(256), 0, stream, beta, coords, asso, rs,
                       w, repb, w + A_LSE, p6p, out, N);
    hipLaunchKernelGGL(k_p5, dim3(1), dim3(1024), 0, stream, rs, w, p6p, nb6, out);
}

// Round 9
// 65.096 us; speedup vs baseline: 1.2702x; 1.1116x over previous
//
#include <hip/hip_runtime.h>

#define NB1 64
#define B_RS 4

// workspace float offsets
#define W_K    0         // [64][1024] u64 packed (fkey<<32 | idx)  = 131072 fl
#define W_C    131072    // [64][1024] u32 counts
#define W_SB   196608    // [64][1024] f32 sum_b
#define W_SP   262144    // [64][1024] f32 p_sum
#define W_NS   327680    // [64][8] noise (cnt,sum per row)
#define A_CY0  328192    // 1024 float4 (-2x lo)
#define A_CY1  332288    // 1024 float4 (-2x hi)
#define A_LM   336384    // 1024 float2 (ck2+1e-6, cf)
#define A_EM   338432    // 1024 float4 (qa, psum, keym_bits, 0)
#define A_SBM  342528    // 1024 merged sum_b
#define A_NKM  343552    // 1024 u32 merged count
#define A_OC   344576    // 4 obj_cnt per row (+4 pad)
#define A_LSE  344584    // 8 x 1024 LSE slices
#define A_PP   352776    // p4 row partials nb*8

__device__ __forceinline__ unsigned fkey(float f) {
    unsigned u = __float_as_uint(f);
    return ((int)u < 0) ? ~u : (u | 0x80000000u);
}
__device__ __forceinline__ float fdec(unsigned k) {
    unsigned u = ((int)k < 0) ? (k & 0x7fffffffu) : ~k;
    return __uint_as_float(u);
}

// ---- P1: block-local LDS aggregation, private-slice flush ----
__global__ __launch_bounds__(512) void k_p1(const float* __restrict__ beta,
                                            const int* __restrict__ asso,
                                            const int* __restrict__ rs,
                                            float* __restrict__ w, int N) {
    __shared__ unsigned long long sk[1024];
    __shared__ unsigned sc[1024];
    __shared__ float ssb[1024], ssp[1024];
    __shared__ float ns[8];
    int t = threadIdx.x, b = blockIdx.x;
    for (int j = t; j < 1024; j += 512) { sk[j] = 0ull; sc[j] = 0u; ssb[j] = 0.f; ssp[j] = 0.f; }
    if (t < 8) ns[t] = 0.f;
    int rs1 = rs[1], rs2 = rs[2], rs3 = rs[3];
    __syncthreads();
    for (int i = b * 512 + t; i < N; i += NB1 * 512) {
        float bv = beta[i];
        int a = asso[i];
        float bc = fminf(fmaxf(bv, 0.f), 0.999f);
        float ath = 0.5f * __logf(__fdividef(1.f + bc, 1.f - bc));
        float at2 = ath * ath;
        float pv = fmaxf(at2, 1e-6f);
        if (a >= 0) {
            unsigned long long pk = (((unsigned long long)fkey(bv)) << 32) | (unsigned)i;
            atomicMax(&sk[a], pk);
            atomicAdd(&sc[a], 1u);
            atomicAdd(&ssb[a], bv);
            atomicAdd(&ssp[a], pv);
        } else {
            int r = (i >= rs1) + (i >= rs2) + (i >= rs3);
            atomicAdd(&ns[2 * r], 1.f);
            atomicAdd(&ns[2 * r + 1], bv);
        }
    }
    __syncthreads();
    for (int j = t; j < 1024; j += 512) {
        ((unsigned long long*)w)[(b << 10) + j] = sk[j];
        ((unsigned*)w)[W_C + (b << 10) + j] = sc[j];
        w[W_SB + (b << 10) + j] = ssb[j];
        w[W_SP + (b << 10) + j] = ssp[j];
    }
    if (t < 8) w[W_NS + b * 8 + t] = ns[t];
}

// ---- M1: merge slices, build staged cluster tables, obj_cnt, zero LSE ----
__global__ __launch_bounds__(256) void k_m1(const float* __restrict__ beta,
                                            const float* __restrict__ coords,
                                            const int* __restrict__ rs,
                                            float* __restrict__ w) {
    __shared__ int oc0;
    int t = threadIdx.x, r = blockIdx.x;
    if (t == 0) oc0 = 0;
    int k = (r << 8) + t;
    unsigned long long k64 = 0ull;
    unsigned cnt = 0u;
    float sb = 0.f, sp = 0.f;
#pragma unroll 4
    for (int rp = 0; rp < NB1; ++rp) {
        unsigned long long v = ((const unsigned long long*)w)[(rp << 10) + k];
        k64 = v > k64 ? v : k64;
        cnt += ((const unsigned*)w)[W_C + (rp << 10) + k];
        sb += w[W_SB + (rp << 10) + k];
        sp += w[W_SP + (rp << 10) + k];
    }
    bool ov = cnt > 0u;
    int ai = (int)(unsigned)(k64 & 0xffffffffull);
    float4 x0 = ((const float4*)coords)[ai * 2];
    float4 x1 = ((const float4*)coords)[ai * 2 + 1];
    float ba = beta[ai];
    float bca = fminf(fmaxf(ba, 0.f), 0.999f);
    float ata = atanhf(bca);
    float qa = ov ? ata * ata + 0.1f : 0.f;
    float cf = qa / fmaxf((float)cnt, 1.f);
    ((float4*)(w + A_CY0))[k] = make_float4(-2.f * x0.x, -2.f * x0.y, -2.f * x0.z, -2.f * x0.w);
    ((float4*)(w + A_CY1))[k] = make_float4(-2.f * x1.x, -2.f * x1.y, -2.f * x1.z, -2.f * x1.w);
    float ck2 = x0.x * x0.x + x0.y * x0.y + x0.z * x0.z + x0.w * x0.w +
                x1.x * x1.x + x1.y * x1.y + x1.z * x1.z + x1.w * x1.w;
    ((float2*)(w + A_LM))[k] = make_float2(ck2 + 1e-6f, cf);
    ((float4*)(w + A_EM))[k] = make_float4(qa, sp, __uint_as_float((unsigned)(k64 >> 32)), 0.f);
    w[A_SBM + k] = sb;
    ((unsigned*)w)[A_NKM + k] = cnt;
    for (int j = t; j < 2048; j += 256) w[A_LSE + (r << 11) + j] = 0.f;
    __syncthreads();
    unsigned long long bal = __ballot(ov);
    if ((t & 63) == 0) atomicAdd(&oc0, __popcll(bal));
    __syncthreads();
    if (t == 0) w[A_OC + r] = (float)oc0;
}

// ---- P4: repulsion over own row's 256 staged clusters + fully fused epilogue ----
__global__ __launch_bounds__(256) void k_p4(const float* __restrict__ beta,
                                            const float* __restrict__ coords,
                                            const int* __restrict__ asso,
                                            const int* __restrict__ rs,
                                            const float* __restrict__ wc,
                                            float* __restrict__ lse,
                                            float* __restrict__ pp,
                                            float* __restrict__ out, int N) {
    __shared__ float4 sY0[512];
    __shared__ float4 sY1[512];
    __shared__ float2 sLM[512];
    __shared__ float4 sEM[512];
    __shared__ float sOC[4];
    __shared__ float bins[8];
    int t = threadIdx.x, bid = blockIdx.x;
    int base = bid << 8;
    int rs1 = rs[1], rs2 = rs[2], rs3 = rs[3];
    int r0 = (base >= rs1) + (base >= rs2) + (base >= rs3);
    int lastp = min(base + 255, N - 1);
    int rl = (lastp >= rs1) + (lastp >= rs2) + (lastp >= rs3);
    {
        const float4* cy0 = (const float4*)(wc + A_CY0);
        const float4* cy1 = (const float4*)(wc + A_CY1);
        const float2* lm = (const float2*)(wc + A_LM);
        const float4* em = (const float4*)(wc + A_EM);
        int k0 = (r0 << 8) + t;
        sY0[t] = cy0[k0]; sY1[t] = cy1[k0]; sLM[t] = lm[k0]; sEM[t] = em[k0];
        if (rl != r0) {
            int k1 = (rl << 8) + t;
            sY0[256 + t] = cy0[k1]; sY1[256 + t] = cy1[k1];
            sLM[256 + t] = lm[k1]; sEM[256 + t] = em[k1];
        }
    }
    if (t < 4) sOC[t] = wc[A_OC + t];
    if (t < 8) bins[t] = 0.f;
    __syncthreads();
    int i = base + t;
    float att = 0.f, rep = 0.f;
    int r = r0;
    if (i < N) {
        const float4* cp = (const float4*)(coords + (size_t)i * 8);
        float4 c0 = cp[0], c1 = cp[1];
        float cn2 = c0.x * c0.x + c0.y * c0.y + c0.z * c0.z + c0.w * c0.w +
                    c1.x * c1.x + c1.y * c1.y + c1.z * c1.z + c1.w * c1.w;
        r = (i >= rs1) + (i >= rs2) + (i >= rs3);
        int s = (r == r0) ? 0 : 256;
        float acc = 0.f;
#pragma unroll 4
        for (int j = s; j < s + 256; ++j) {
            float4 y0 = sY0[j];
            float4 y1 = sY1[j];
            float2 cm = sLM[j];
            float d = cn2 + cm.x;
            d = fmaf(y0.x, c0.x, d); d = fmaf(y0.y, c0.y, d);
            d = fmaf(y0.z, c0.z, d); d = fmaf(y0.w, c0.w, d);
            d = fmaf(y1.x, c1.x, d); d = fmaf(y1.y, c1.y, d);
            d = fmaf(y1.z, c1.z, d); d = fmaf(y1.w, c1.w, d);
            d = fmaxf(d, 1e-6f);
            float v = fmaxf(1.f - sqrtf(d), 0.f);
            acc = fmaf(v, cm.y, acc);
        }
        float bv = beta[i];
        int aa = asso[i];
        float bc = fminf(fmaxf(bv, 0.f), 0.999f);
        float ath = 0.5f * __logf(__fdividef(1.f + bc, 1.f - bc));
        float at2 = ath * ath;
        float q = at2 + 0.1f;
        float pv = fmaxf(at2, 1e-6f);
        bool valid = aa >= 0;
        float pl = 0.f;
        if (valid) {
            int slot = (((aa >> 8) == r0) ? 0 : 256) + (aa & 255);
            float4 y0 = sY0[slot], y1 = sY1[slot];
            float2 cm = sLM[slot];
            float4 emv = sEM[slot];
            // attraction via exact alpha coords x = -0.5 * y
            float d0 = c0.x + 0.5f * y0.x, d1 = c0.y + 0.5f * y0.y;
            float d2 = c0.z + 0.5f * y0.z, d3 = c0.w + 0.5f * y0.w;
            float d4 = c1.x + 0.5f * y1.x, d5 = c1.y + 0.5f * y1.y;
            float d6 = c1.z + 0.5f * y1.z, d7 = c1.w + 0.5f * y1.w;
            float dsq = d0 * d0 + d1 * d1 + d2 * d2 + d3 * d3 +
                        d4 * d4 + d5 * d5 + d6 * d6 + d7 * d7;
            att = q * emv.x * dsq;
            // subtract own-cluster contribution (same arithmetic as loop)
            float d = cn2 + cm.x;
            d = fmaf(y0.x, c0.x, d); d = fmaf(y0.y, c0.y, d);
            d = fmaf(y0.z, c0.z, d); d = fmaf(y0.w, c0.w, d);
            d = fmaf(y1.x, c1.x, d); d = fmaf(y1.y, c1.y, d);
            d = fmaf(y1.z, c1.z, d); d = fmaf(y1.w, c1.w, d);
            d = fmaxf(d, 1e-6f);
            acc -= fmaxf(1.f - sqrtf(d), 0.f) * cm.y;
            // LSE partial
            float m = fdec(__float_as_uint(emv.z));
            atomicAdd(&lse[((bid & 7) << 10) + aa], __expf((bv - m) * 1000.f));
            pl = pv / fmaxf(emv.y, 1e-6f) / fmaxf(sOC[r], 1.f) * 0.25f;
        }
        rep = q * acc;
        out[3 + i] = pl;
        out[3 + N + i] = att + rep;
    }
    int lane = t & 63;
    int rA = __shfl(r, 0);
    bool uni = __all(r == rA);
    if (uni) {
        float aS = att, rS = rep;
#pragma unroll
        for (int o = 32; o; o >>= 1) { aS += __shfl_xor(aS, o); rS += __shfl_xor(rS, o); }
        if (lane == 0) { atomicAdd(&bins[rA], aS); atomicAdd(&bins[4 + rA], rS); }
    } else if (i < N) {
        atomicAdd(&bins[r], att);
        atomicAdd(&bins[4 + r], rep);
    }
    __syncthreads();
    if (t < 8) pp[bid * 8 + t] = bins[t];
}

// ---- P5: bpen + all final reductions ----
__global__ __launch_bounds__(1024) void k_p5(const int* __restrict__ rs,
                                             const float* __restrict__ w,
                                             const float* __restrict__ pp, int nb,
                                             float* __restrict__ out) {
    __shared__ float op[4];
    __shared__ float nsb[8];
    __shared__ float ar8[8][9];
    int t = threadIdx.x;
    if (t < 4) op[t] = 0.f;
    __syncthreads();
    int k = t;
    float ls = 0.f;
#pragma unroll
    for (int rp = 0; rp < 8; ++rp) ls += w[A_LSE + (rp << 10) + k];
    unsigned cnt = ((const unsigned*)w)[A_NKM + k];
    bool ov = cnt > 0u;
    float4 emv = ((const float4*)(w + A_EM))[k];
    float m = ov ? fdec(__float_as_uint(emv.z)) : 0.f;
    float lsev = m + 0.001f * logf(ls + 1e-30f);
    float sbc = fminf(fmaxf(w[A_SBM + k], 0.f), 1.f);
    float bpen = ov ? (1.f - lsev) + (1.f - sbc) : 0.f;
    float v = bpen;
#pragma unroll
    for (int o = 32; o; o >>= 1) v += __shfl_xor(v, o);
    if ((t & 63) == 0) atomicAdd(&op[k >> 8], v);
    if (t < 64) {
        int slot = t & 7, part = t >> 3;
        float acc = 0.f;
        for (int j = part; j < nb; j += 8) acc += pp[j * 8 + slot];
        ar8[slot][part] = acc;
    } else if (t < 72) {
        int s = t - 64;
        float a = 0.f;
        for (int b = 0; b < NB1; ++b) a += w[W_NS + b * 8 + s];
        nsb[s] = a;
    }
    __syncthreads();
    if (t == 0) {
        float lv = 0.f, lr = 0.f, lb = 0.f;
        for (int r = 0; r < B_RS; ++r) {
            float a = 0.f, rp = 0.f;
            for (int j = 0; j < 8; ++j) { a += ar8[r][j]; rp += ar8[4 + r][j]; }
            float len = (float)(rs[r + 1] - rs[r]);
            lv += a / len;
            lr += rp / len;
            float oc = w[A_OC + r];
            lb += op[r] / fmaxf(oc, 1.f) + nsb[2 * r + 1] / fmaxf(nsb[2 * r], 1.f);
        }
        out[0] = lv * 0.25f;
        out[1] = lr * 0.25f;
        out[2] = lb * 0.25f;
    }
}

extern "C" void kernel_launch(void* const* d_in, const int* in_sizes, int n_in,
                              void* d_out, int out_size, void* d_ws, size_t ws_size,
                              hipStream_t stream) {
    const float* beta = (const float*)d_in[0];
    const float* coords = (const float*)d_in[1];
    const int* asso = (const int*)d_in[2];
    const int* rs = (const int*)d_in[3];
    int N = in_sizes[0];
    float* w = (float*)d_ws;
    float* out = (float*)d_out;
    int nb = (N + 255) / 256;
    hipLaunchKernelGGL(k_p1, dim3(NB1), dim3(512), 0, stream, beta, asso, rs, w, N);
    hipLaunchKernelGGL(k_m1, dim3(4), dim3(256), 0, stream, beta, coords, rs, w);
    hipLaunchKernelGGL(k_p4, dim3(nb), dim3(256), 0, stream, beta, coords, asso, rs,
                       w, w + A_LSE, w + A_PP, out, N);
    hipLaunchKernelGGL(k_p5, dim3(1), dim3(1024), 0, stream, rs, w, w + A_PP, nb, out);
}